// Round 5
// baseline (387.700 us; speedup 1.0000x reference)
//
#include <hip/hip_runtime.h>

#define NB 1024
#define NL 512
#define ND 1000   // ATTN
#define NH 1000   // HID
#define KP 2048   // padded K (= NH + ND padded to 2048)

typedef __attribute__((ext_vector_type(8))) short bf16x8;
typedef __attribute__((ext_vector_type(4))) float f32x4;

__device__ __forceinline__ unsigned short f2bf(float f) {
    unsigned u = __float_as_uint(f);
    u += 0x7FFFu + ((u >> 16) & 1u);     // RNE
    return (unsigned short)(u >> 16);
}

// -------- Kernel 0: prep — convert hc and Wc_w to bf16 (padded) --------
__global__ __launch_bounds__(256) void prep_kernel(
    const float* __restrict__ hc, const float* __restrict__ W,
    unsigned short* __restrict__ Xb, unsigned short* __restrict__ Wb)
{
    const int bid = blockIdx.x, t = threadIdx.x;
    if (bid < NB) {
        ushort4* xq = (ushort4*)(Xb + (size_t)bid * KP);
        if (t < 250) {
            float4 v = ((const float4*)(hc + (size_t)bid * NH))[t];
            xq[t] = make_ushort4(f2bf(v.x), f2bf(v.y), f2bf(v.z), f2bf(v.w));
        } else if (t < 262) {
            xq[500 + (t - 250)] = make_ushort4(0, 0, 0, 0);
        }
    } else {
        const int n = bid - NB;
        ushort4* wq = (ushort4*)(Wb + (size_t)n * KP);
        if (n < NH) {
            #pragma unroll
            for (int rep = 0; rep < 2; ++rep) {
                int q = t + rep * 256;
                if (q < 500) {
                    float4 v = ((const float4*)(W + (size_t)n * (NH + ND)))[q];
                    wq[q] = make_ushort4(f2bf(v.x), f2bf(v.y), f2bf(v.z), f2bf(v.w));
                } else {
                    wq[q] = make_ushort4(0, 0, 0, 0);
                }
            }
        } else {
            wq[t]       = make_ushort4(0, 0, 0, 0);
            wq[t + 256] = make_ushort4(0, 0, 0, 0);
        }
    }
}

// -------- Kernel 1: fused scores -> online softmax -> context --------
// Register-pipelined single pass (as R4), but loads use 128B-ALIGNED 4096B
// windows: wave w owns rows l = 4c+w, whose base misalignment is wave-constant
// (4000l mod 128 = 32w). Window = row_base - 32w bytes (= 2w float4 slots).
// Wa fragment and epilogue store indices are pre-shifted by 2w to compensate;
// junk slots (head: k<2w, tail: k>249+2w) get wa=0 and are never stored.
__global__ __launch_bounds__(256, 4) void attn_pool_kernel(
    const float* __restrict__ ho,           // [NB, NL, ND]
    const unsigned char* __restrict__ mask, // [NB, NL]
    const float* __restrict__ Wa_w,         // [ND]
    const float* __restrict__ Wa_b,         // [1]
    unsigned short* __restrict__ Xb)        // [NB, KP] bf16, cols 1000..1999
{
    __shared__ __align__(16) float cacc[4][ND];   // 16000 B combine scratch
    __shared__ unsigned char msk[NL];
    __shared__ float mArr[4], sArr[4];

    const int b    = blockIdx.x;
    const int tid  = threadIdx.x;
    const int wave = tid >> 6;
    const int lane = tid & 63;
    const int sh   = 2 * wave;     // float4-slot shift of this wave's windows

    const unsigned char* mb = mask + (size_t)b * NL;
    msk[tid]       = mb[tid];
    msk[tid + 256] = mb[tid + 256];

    // Wa fragment, pre-shifted: window slot k = lane+64j holds row slot k-sh
    float4 wa[4];
    #pragma unroll
    for (int j = 0; j < 4; ++j) {
        int src = lane + 64 * j - sh;
        wa[j] = (src >= 0 && src < 250) ? ((const float4*)Wa_w)[src]
                                        : make_float4(0.f, 0.f, 0.f, 0.f);
    }
    const float bias = Wa_b[0];

    const char* B0   = (const char*)ho + (size_t)b * (NL * ND) * 4;
    const char* gend = (const char*)ho + ((size_t)NB * NL * ND) * 4 - 16;

    __syncthreads();  // masks visible

    // aligned-window row load: 4096B window at row_base - 32w (128B-aligned)
    auto loadRow = [&](int l, float4* v) {
        const char* wbase = B0 + (size_t)4000 * l - 16 * sh;
        #pragma unroll
        for (int j = 0; j < 3; ++j)
            v[j] = *(const float4*)(wbase + (size_t)(lane + 64 * j) * 16);
        const char* p3 = wbase + (size_t)(lane + 192) * 16;
        if (p3 > gend) p3 = gend;          // clamp only at absolute tensor end
        v[3] = *(const float4*)p3;
    };

    float  m = -1e30f, s = 0.f;
    float4 acc[4];
    #pragma unroll
    for (int j = 0; j < 4; ++j) acc[j] = make_float4(0.f, 0.f, 0.f, 0.f);

    float4 cur[4], nx1[4], nx2[4];
    loadRow(wave, cur);
    loadRow(4 + wave, nx1);

    #pragma unroll 2
    for (int c = 0; c < 128; ++c) {
        if (c + 2 < 128) loadRow(4 * (c + 2) + wave, nx2);

        float p = 0.f;
        #pragma unroll
        for (int j = 0; j < 4; ++j)
            p += cur[j].x * wa[j].x + cur[j].y * wa[j].y +
                 cur[j].z * wa[j].z + cur[j].w * wa[j].w;
        #pragma unroll
        for (int off = 32; off > 0; off >>= 1) p += __shfl_xor(p, off, 64);

        int l = 4 * c + wave;
        float sc = p + bias;
        if (msk[l]) sc = -10000.f;

        float mn = fmaxf(m, sc);
        if (mn > m) {                       // wave-uniform branch
            float f = __expf(m - mn);
            s *= f;
            #pragma unroll
            for (int j = 0; j < 4; ++j) {
                acc[j].x *= f; acc[j].y *= f; acc[j].z *= f; acc[j].w *= f;
            }
            m = mn;
        }
        float w = __expf(sc - m);
        s += w;
        #pragma unroll
        for (int j = 0; j < 4; ++j) {
            acc[j].x += w * cur[j].x; acc[j].y += w * cur[j].y;
            acc[j].z += w * cur[j].z; acc[j].w += w * cur[j].w;
        }

        #pragma unroll
        for (int j = 0; j < 4; ++j) { cur[j] = nx1[j]; nx1[j] = nx2[j]; }
    }

    // ---- flash-combine the 4 per-wave partials (store at shifted index) ----
    float4* cw = (float4*)&cacc[wave][0];   // 250 float4 per wave
    #pragma unroll
    for (int j = 0; j < 4; ++j) {
        int s2 = lane + 64 * j - sh;        // row slot
        if (s2 >= 0 && s2 < 250) cw[s2] = acc[j];
    }
    if (lane == 0) { mArr[wave] = m; sArr[wave] = s; }
    __syncthreads();

    float gm = fmaxf(fmaxf(mArr[0], mArr[1]), fmaxf(mArr[2], mArr[3]));
    float f0 = __expf(mArr[0] - gm), f1 = __expf(mArr[1] - gm);
    float f2 = __expf(mArr[2] - gm), f3 = __expf(mArr[3] - gm);
    float S  = f0 * sArr[0] + f1 * sArr[1] + f2 * sArr[2] + f3 * sArr[3];
    float inv = 1.0f / S;

    if (tid < 250) {
        float4 a0 = ((float4*)&cacc[0][0])[tid];
        float4 a1 = ((float4*)&cacc[1][0])[tid];
        float4 a2 = ((float4*)&cacc[2][0])[tid];
        float4 a3 = ((float4*)&cacc[3][0])[tid];
        float4 r;
        r.x = (f0 * a0.x + f1 * a1.x + f2 * a2.x + f3 * a3.x) * inv;
        r.y = (f0 * a0.y + f1 * a1.y + f2 * a2.y + f3 * a3.y) * inv;
        r.z = (f0 * a0.z + f1 * a1.z + f2 * a2.z + f3 * a3.z) * inv;
        r.w = (f0 * a0.w + f1 * a1.w + f2 * a2.w + f3 * a3.w) * inv;
        ((ushort4*)(Xb + (size_t)b * KP + ND))[tid] =
            make_ushort4(f2bf(r.x), f2bf(r.y), f2bf(r.z), f2bf(r.w));
    }
}

// -------- Kernel 2: bf16 MFMA projection: out = Xb @ Wb^T + bias --------
__global__ __launch_bounds__(256, 1) void mfma_proj_kernel(
    const unsigned short* __restrict__ Xb,   // [NB][KP] bf16
    const unsigned short* __restrict__ Wb,   // [1024][KP] bf16
    const float* __restrict__ wb,            // [NH]
    float* __restrict__ out)                 // [NB][NH]
{
    __shared__ float red[64][65];

    const int tid  = threadIdx.x;
    const int wave = tid >> 6;
    const int lane = tid & 63;
    const int row0 = blockIdx.x * 64;
    const int col0 = blockIdx.y * 64;
    const int r    = lane & 15;
    const int g    = lane >> 4;

    const int kbase = wave * 512 + g * 8;
    const unsigned short* xp = Xb + (size_t)(row0 + r) * KP + kbase;
    const unsigned short* wp = Wb + (size_t)(col0 + r) * KP + kbase;

    f32x4 acc[4][4];
    #pragma unroll
    for (int mi = 0; mi < 4; ++mi)
        #pragma unroll
        for (int ni = 0; ni < 4; ++ni)
            acc[mi][ni] = (f32x4){0.f, 0.f, 0.f, 0.f};

    bf16x8 a_[4], b_[4], an[4], bn[4];
    #pragma unroll
    for (int i = 0; i < 4; ++i) {
        a_[i] = *(const bf16x8*)(xp + (size_t)i * 16 * KP);
        b_[i] = *(const bf16x8*)(wp + (size_t)i * 16 * KP);
    }

    #pragma unroll 1
    for (int ks = 0; ks < 16; ++ks) {
        if (ks + 1 < 16) {
            const unsigned short* xq = xp + (ks + 1) * 32;
            const unsigned short* wq = wp + (ks + 1) * 32;
            #pragma unroll
            for (int i = 0; i < 4; ++i) {
                an[i] = *(const bf16x8*)(xq + (size_t)i * 16 * KP);
                bn[i] = *(const bf16x8*)(wq + (size_t)i * 16 * KP);
            }
        }
        #pragma unroll
        for (int mi = 0; mi < 4; ++mi)
            #pragma unroll
            for (int ni = 0; ni < 4; ++ni)
                acc[mi][ni] = __builtin_amdgcn_mfma_f32_16x16x32_bf16(
                    a_[mi], b_[ni], acc[mi][ni], 0, 0, 0);
        #pragma unroll
        for (int i = 0; i < 4; ++i) { a_[i] = an[i]; b_[i] = bn[i]; }
    }

    // ---- cross-wave reduce (serialized, 4 phases) ----
    #pragma unroll
    for (int w = 0; w < 4; ++w) {
        if (wave == w) {
            #pragma unroll
            for (int mi = 0; mi < 4; ++mi)
                #pragma unroll
                for (int ni = 0; ni < 4; ++ni)
                    #pragma unroll
                    for (int j = 0; j < 4; ++j) {
                        int rr = mi * 16 + g * 4 + j;   // C/D: row=(lane>>4)*4+reg
                        int cc = ni * 16 + r;           // C/D: col=lane&15
                        float v = acc[mi][ni][j];
                        if (w == 0) red[rr][cc] = v;
                        else        red[rr][cc] += v;
                    }
        }
        __syncthreads();
    }

    // ---- store + bias ----
    const int cc = tid & 63;
    const int rg = tid >> 6;
    const int gc = col0 + cc;
    if (gc < NH) {
        float bias = wb[gc];
        #pragma unroll
        for (int i = 0; i < 16; ++i) {
            int rr = rg * 16 + i;
            out[(size_t)(row0 + rr) * NH + gc] = red[rr][cc] + bias;
        }
    }
}

extern "C" void kernel_launch(void* const* d_in, const int* in_sizes, int n_in,
                              void* d_out, int out_size, void* d_ws, size_t ws_size,
                              hipStream_t stream) {
    const float* hc           = (const float*)d_in[0];
    const float* ho           = (const float*)d_in[1];
    const unsigned char* mask = (const unsigned char*)d_in[2];
    const float* Wa_w         = (const float*)d_in[3];
    const float* Wa_b         = (const float*)d_in[4];
    const float* Wc_w         = (const float*)d_in[5];
    const float* Wc_b         = (const float*)d_in[6];
    float* out = (float*)d_out;

    unsigned short* Xb = (unsigned short*)d_ws;                       // 1024*2048 bf16 = 4 MB
    unsigned short* Wb = (unsigned short*)d_ws + (size_t)NB * KP;     // 1024*2048 bf16 = 4 MB

    prep_kernel<<<2048, 256, 0, stream>>>(hc, Wc_w, Xb, Wb);
    attn_pool_kernel<<<NB, 256, 0, stream>>>(ho, mask, Wa_w, Wa_b, Xb);
    mfma_proj_kernel<<<dim3(16, 16), 256, 0, stream>>>(Xb, Wb, Wc_b, out);
}